// Round 12
// baseline (51.458 us; speedup 1.0000x reference)
//
#include <hip/hip_runtime.h>
#include <math.h>

// Problem dims (fixed by setup_inputs)
#define NROWS 8192   // B*T = 4*2048
#define DD    1024
#define HH    256
#define NTT   32
#define NCOLS 288    // HH + NTT

typedef __attribute__((ext_vector_type(8))) __bf16 bf16x8;
typedef __attribute__((ext_vector_type(4))) float f32x4;
typedef __attribute__((ext_vector_type(8))) unsigned short ushort8_t;

static __device__ __forceinline__ unsigned short f2bf(float f) {
    unsigned int u = __float_as_uint(f);
    unsigned int r = (u + 0x7fffu + ((u >> 16) & 1u)) >> 16;
    return (unsigned short)r;
}

static __device__ __forceinline__ float sgnf(float x) {
    return x > 0.0f ? 1.0f : (x < 0.0f ? -1.0f : 0.0f);
}

static __device__ __forceinline__ float ternf(float x) {
    return x > 0.3f ? 1.0f : (x < -0.3f ? -1.0f : 0.0f);
}

static __device__ __forceinline__ float bspline(float u) {
    float t = fabsf(u);
    if (t < 1.0f) return 0.66666666666666663f - t * t + 0.5f * t * t * t;
    if (t < 2.0f) { float w = 2.0f - t; return 0.16666666666666666f * w * w * w; }
    return 0.0f;
}

// ---------------- K0: merged prep (grid 288, atomics; colsum/bw pre-zeroed) ----
__global__ __launch_bounds__(256) void k_prep(const float* __restrict__ W1,
                                              const float* __restrict__ dirs,
                                              const float* __restrict__ gamma,
                                              const float* __restrict__ beta,
                                              unsigned short* __restrict__ WT,
                                              float* __restrict__ colsum,
                                              float* __restrict__ bwv) {
    int bid = blockIdx.x;
    int tid = threadIdx.x;
    if (bid < 256) {
        __shared__ float tile[32][33];
        __shared__ float redg[8][32];
        __shared__ float redb[8][32];
        int ktile = bid & 31;            // d tiles of 32
        int ntile = bid >> 5;            // j tiles of 32
        int tx = tid & 31;
        int ty = tid >> 5;               // 0..7
        float sg = 0.f, sb = 0.f;
#pragma unroll
        for (int i = 0; i < 4; ++i) {
            int k = ktile * 32 + ty + i * 8;
            int n = ntile * 32 + tx;
            float w = W1[(size_t)k * HH + n];        // coalesced over n
            float gk = gamma[k];
            tile[ty + i * 8][tx] = w * gk;
            sg += w * gk;
            sb += w * beta[k];
        }
        redg[ty][tx] = sg;
        redb[ty][tx] = sb;
        __syncthreads();
#pragma unroll
        for (int i = 0; i < 4; ++i) {
            int n = ntile * 32 + ty + i * 8;
            int k = ktile * 32 + tx;
            WT[(size_t)n * DD + k] = f2bf(tile[tx][ty + i * 8]);  // coalesced over k
        }
        if (ty == 0) {
            float a = 0.f, c = 0.f;
#pragma unroll
            for (int k = 0; k < 8; ++k) { a += redg[k][tx]; c += redb[k][tx]; }
            int j = ntile * 32 + tx;
            atomicAdd(&colsum[j], a);
            atomicAdd(&bwv[j], c);
        }
    } else {
        int r = bid - 256;               // 0..31
        float4 v  = ((const float4*)(dirs + (size_t)r * DD))[tid];
        float4 g  = ((const float4*)gamma)[tid];
        float4 be = ((const float4*)beta)[tid];
        float s0 = sgnf(v.x), s1 = sgnf(v.y), s2 = sgnf(v.z), s3 = sgnf(v.w);
        ushort4 o;
        o.x = f2bf(s0 * g.x); o.y = f2bf(s1 * g.y);
        o.z = f2bf(s2 * g.z); o.w = f2bf(s3 * g.w);
        ((ushort4*)(WT + (size_t)(HH + r) * DD))[tid] = o;
        float ps = s0 * g.x + s1 * g.y + s2 * g.z + s3 * g.w;
        float pb = s0 * be.x + s1 * be.y + s2 * be.z + s3 * be.w;
#pragma unroll
        for (int off = 32; off; off >>= 1) {
            ps += __shfl_xor(ps, off);
            pb += __shfl_xor(pb, off);
        }
        __shared__ float red[8];
        int wid = tid >> 6, lane = tid & 63;
        if (lane == 0) { red[wid] = ps; red[wid + 4] = pb; }
        __syncthreads();
        if (tid == 0) {
            colsum[HH + r] = red[0] + red[1] + red[2] + red[3];
            bwv[HH + r]    = red[4] + red[5] + red[6] + red[7];
        }
    }
}

// ---------------- K1: LN-fused GEMM, MAX OCCUPANCY ----------------
// HP[row][j] = rstd*(x_row @ WT_j) - mu*rstd*colsum[j] + bw[j]
// BM=16, BN=96, BK=64; 6 waves (384 thr), wave tile 16x16 (acc = 1 f32x4).
// LDS: A 2x2KB + B 2x12KB = 28KB -> 5 blocks/CU x 6 waves = 30 waves/CU.
// Grid (3,512) = 1536 blocks, bijective XCD swizzle (1536 = 8*192) so the 3
// col-blocks sharing x-rows land on the same XCD L2. Simple 2-barrier/kt
// m97-style loop - barrier drains overlap across the 5 resident blocks.
#define GTHR 384
__global__ __launch_bounds__(GTHR, 6) void k_gemm(const float* __restrict__ x,
                                                  const unsigned short* __restrict__ WT,
                                                  const float* __restrict__ colsum,
                                                  const float* __restrict__ bwv,
                                                  float* __restrict__ HP) {
    __shared__ short Al[2][16 * 64];   // 2 x 2KB
    __shared__ short Bl[2][96 * 64];   // 2 x 12KB
    __shared__ float stats[16][2];
    int tid = threadIdx.x;
    int bid = blockIdx.y * 3 + blockIdx.x;          // 0..1535
    int swz = (bid & 7) * 192 + (bid >> 3);         // bijective XCD swizzle
    int colblk = swz % 3;
    int rowblk = swz / 3;
    int row0  = rowblk * 16;
    int ncol0 = colblk * 96;
    int lane = tid & 63;
    int wid  = tid >> 6;               // 0..5 = wave col group (16 cols)
    int l15 = lane & 15, l4 = lane >> 4;

    // A staging: threads 0..127, 8 threads/row, 8 floats (2 float4) each
    int rA = (tid >> 3) & 15;
    int c8 = tid & 7;
    const float* xrow = x + (size_t)(row0 + rA) * DD + c8 * 8;
    int abyte = (rA * 128 + c8 * 16) ^ ((rA & 7) << 4);

    float s = 0.f, sq = 0.f;
    f32x4 acc = (f32x4){0.f, 0.f, 0.f, 0.f};

#define STAGE(kt, buf)                                                           \
    {                                                                            \
        _Pragma("unroll")                                                        \
        for (int ci = 0; ci < 2; ++ci) {                                         \
            int li = ci * GTHR + tid;                                            \
            int r  = li >> 3;                                                    \
            int g  = li & 7;                                                     \
            const unsigned short* src =                                          \
                WT + (size_t)(ncol0 + r) * DD + (kt) * 64 + ((g * 8) ^ ((r & 7) << 3)); \
            __builtin_amdgcn_global_load_lds(                                    \
                (const __attribute__((address_space(1))) void*)(const void*)src, \
                (__attribute__((address_space(3))) void*)(void*)(Bl[buf] + li * 8), \
                16, 0, 0);                                                       \
        }                                                                        \
        if (tid < 128) {                                                         \
            float4 v0 = ((const float4*)(xrow + (kt) * 64))[0];                  \
            float4 v1 = ((const float4*)(xrow + (kt) * 64))[1];                  \
            s  += (v0.x + v0.y + v0.z + v0.w) + (v1.x + v1.y + v1.z + v1.w);     \
            sq += (v0.x*v0.x + v0.y*v0.y + v0.z*v0.z + v0.w*v0.w)                \
                + (v1.x*v1.x + v1.y*v1.y + v1.z*v1.z + v1.w*v1.w);               \
            ushort8_t w;                                                         \
            w[0] = f2bf(v0.x); w[1] = f2bf(v0.y); w[2] = f2bf(v0.z); w[3] = f2bf(v0.w); \
            w[4] = f2bf(v1.x); w[5] = f2bf(v1.y); w[6] = f2bf(v1.z); w[7] = f2bf(v1.w); \
            *(ushort8_t*)((char*)Al[buf] + abyte) = w;                           \
        }                                                                        \
    }

#define COMPUTE(buf)                                                             \
    _Pragma("unroll")                                                            \
    for (int ks = 0; ks < 2; ++ks) {                                             \
        int ca = (ks * 64 + l4 * 16) ^ ((l15 & 7) << 4);                         \
        bf16x8 av = *(const bf16x8*)((const char*)Al[buf] + l15 * 128 + ca);     \
        int rb = wid * 16 + l15;                                                 \
        int cb = (ks * 64 + l4 * 16) ^ ((rb & 7) << 4);                          \
        bf16x8 bv = *(const bf16x8*)((const char*)Bl[buf] + rb * 128 + cb);      \
        acc = __builtin_amdgcn_mfma_f32_16x16x32_bf16(av, bv, acc, 0, 0, 0);     \
    }

    STAGE(0, 0);
    __syncthreads();
    for (int kt = 0; kt < 16; ++kt) {
        if (kt < 15) STAGE(kt + 1, (kt + 1) & 1);
        COMPUTE(kt & 1);
        __syncthreads();
    }
#undef STAGE
#undef COMPUTE

    // LN stats finalize: 8 staging threads per row are contiguous lanes
    if (tid < 128) {
        s  += __shfl_xor(s, 1);  s  += __shfl_xor(s, 2);  s  += __shfl_xor(s, 4);
        sq += __shfl_xor(sq, 1); sq += __shfl_xor(sq, 2); sq += __shfl_xor(sq, 4);
        if (c8 == 0) {
            float mu  = s * (1.0f / DD);
            float var = sq * (1.0f / DD) - mu * mu;
            stats[rA][0] = mu;
            stats[rA][1] = rsqrtf(var + 1e-5f);
        }
    }
    __syncthreads();

    // corrected write: D frag layout col=lane&15, row=(lane>>4)*4+i
    {
        int colg = ncol0 + wid * 16 + l15;
        float cs = colsum[colg];
        float bw = bwv[colg];
        int rl0 = l4 * 4;
#pragma unroll
        for (int i = 0; i < 4; ++i) {
            float mu   = stats[rl0 + i][0];
            float rstd = stats[rl0 + i][1];
            HP[(size_t)(row0 + rl0 + i) * NCOLS + colg] =
                rstd * acc[i] - mu * rstd * cs + bw;
        }
    }
}

// ---------------- K2: per-row epilogue + output ----------------
__global__ __launch_bounds__(256) void k_epilogue(
    const float* __restrict__ HP, const float* __restrict__ x,
    const float* __restrict__ positions, const int* __restrict__ states,
    const float* __restrict__ b1, const float* __restrict__ W2,
    const float* __restrict__ b2, const float* __restrict__ spc,
    const float* __restrict__ sps, const float* __restrict__ dirs,
    const float* __restrict__ ssig, const float* __restrict__ semb,
    const float* __restrict__ smod, const float* __restrict__ oscale,
    float* __restrict__ out) {
    int wid = threadIdx.x >> 6;
    int lane = threadIdx.x & 63;
    int row = blockIdx.x * 4 + wid;

    const float* hrow = HP + (size_t)row * NCOLS;
    float4 hv  = ((const float4*)hrow)[lane];          // h_pre[lane*4 .. +3]
    float4 b1v = ((const float4*)b1)[lane];
    float hs[4] = {hv.x, hv.y, hv.z, hv.w};
    float bs[4] = {b1v.x, b1v.y, b1v.z, b1v.w};
    float sa = 0.f, sb = 0.f;
#pragma unroll
    for (int i = 0; i < 4; ++i) {
        float h = hs[i] + bs[i];
        float g = 0.5f * h * (1.0f + erff(h * 0.70710678118654752f));  // exact gelu
        int j = lane * 4 + i;
        sa += g * W2[2 * j];
        sb += g * W2[2 * j + 1];
    }
#pragma unroll
    for (int off = 32; off; off >>= 1) {
        sa += __shfl_xor(sa, off);
        sb += __shfl_xor(sb, off);
    }
    float av = tanhf(sa + b2[0]);
    float bv = tanhf(sb + b2[1]);

    int st = states[row];
    float comb;
    if (lane < NTT) {
        float content = hrow[HH + lane];
        float pn = positions[row] * ((float)NTT / 2048.0f);
        float u  = (pn - (float)lane) * 0.5f;            // /SPREAD
        float spv = bspline(u);
        const float* sg = ssig + lane * 8;
        const float* se = semb + st * 8;
        float d0 = 0.f;
#pragma unroll
        for (int k = 0; k < 8; ++k) d0 += se[k] * sg[k];
        float temporal = 1.0f / (1.0f + expf(-d0));
        comb = content * spv * temporal;
    } else {
        comb = -__builtin_inff();
    }
    int bi = lane;
#pragma unroll
    for (int off = 32; off; off >>= 1) {
        float ov = __shfl_xor(comb, off);
        int   oi = __shfl_xor(bi, off);
        if (ov > comb || (ov == comb && oi < bi)) { comb = ov; bi = oi; }
    }
    int ia = (int)((av + 1.0f) * 8.0f); ia = ia < 0 ? 0 : (ia > 15 ? 15 : ia);
    int ib = (int)((bv + 1.0f) * 8.0f); ib = ib < 0 ? 0 : (ib > 15 ? 15 : ib);
    const float* cc = spc + (((size_t)bi * 16 + ia) * 16 + ib) * 3;
    float c0 = ternf(cc[0]), c1 = ternf(cc[1]), c2 = ternf(cc[2]);
    float la = (av + 1.0f - (float)ia * 0.125f) * 8.0f;
    float lb = (bv + 1.0f - (float)ib * 0.125f) * 8.0f;
    float scale = (c0 + c1 * la + c2 * lb) * sps[bi];
    float sm = smod[st * NTT + bi];
    float cr = scale * sm * oscale[0];

    const float4* xr = (const float4*)(x + (size_t)row * DD);
    const float4* dr = (const float4*)(dirs + (size_t)bi * DD);
    float4* orow = (float4*)(out + (size_t)row * DD);
#pragma unroll
    for (int i = 0; i < 4; ++i) {
        int idx = i * 64 + lane;
        float4 xv = xr[idx];
        float4 dv = dr[idx];
        float4 o;
        o.x = fmaf(cr, dv.x, xv.x);
        o.y = fmaf(cr, dv.y, xv.y);
        o.z = fmaf(cr, dv.z, xv.z);
        o.w = fmaf(cr, dv.w, xv.w);
        orow[idx] = o;
    }
}

extern "C" void kernel_launch(void* const* d_in, const int* in_sizes, int n_in,
                              void* d_out, int out_size, void* d_ws, size_t ws_size,
                              hipStream_t stream) {
    const float* x     = (const float*)d_in[0];
    const float* pos   = (const float*)d_in[1];
    const int*   st    = (const int*)d_in[2];
    const float* gam   = (const float*)d_in[3];
    const float* bet   = (const float*)d_in[4];
    const float* W1    = (const float*)d_in[5];
    const float* b1    = (const float*)d_in[6];
    const float* W2    = (const float*)d_in[7];
    const float* b2    = (const float*)d_in[8];
    const float* spc   = (const float*)d_in[9];
    const float* sps   = (const float*)d_in[10];
    const float* dirs  = (const float*)d_in[11];
    const float* ssig  = (const float*)d_in[12];
    const float* semb  = (const float*)d_in[13];
    const float* smod  = (const float*)d_in[14];
    const float* oscal = (const float*)d_in[15];
    float* out = (float*)d_out;

    char* ws = (char*)d_ws;
    unsigned short* WT = (unsigned short*)ws;                  // 288*1024 bf16 = 576 KiB
    float* colsum = (float*)(ws + 589824);                     // 288 f32
    float* bwv    = (float*)(ws + 589824 + 288 * 4);           // 288 f32 (contiguous)
    float* HP     = (float*)(ws + 1048576);                    // 8192*288 f32 = 9 MiB

    hipMemsetAsync(colsum, 0, 2 * 288 * sizeof(float), stream);
    k_prep<<<288, 256, 0, stream>>>(W1, dirs, gam, bet, WT, colsum, bwv);
    k_gemm<<<dim3(3, 512), GTHR, 0, stream>>>(x, WT, colsum, bwv, HP);
    k_epilogue<<<NROWS / 4, 256, 0, stream>>>(HP, x, pos, st, b1, W2, b2, spc, sps,
                                              dirs, ssig, semb, smod, oscal, out);
}

// Round 13
// 48.025 us; speedup vs baseline: 1.0715x; 1.0715x over previous
//
#include <hip/hip_runtime.h>
#include <math.h>

// Problem dims (fixed by setup_inputs)
#define NROWS 8192   // B*T = 4*2048
#define DD    1024
#define HH    256
#define NTT   32
#define NCOLS 288    // HH + NTT

typedef __attribute__((ext_vector_type(8))) __bf16 bf16x8;
typedef __attribute__((ext_vector_type(4))) float f32x4;

static __device__ __forceinline__ unsigned short f2bf(float f) {
    unsigned int u = __float_as_uint(f);
    unsigned int r = (u + 0x7fffu + ((u >> 16) & 1u)) >> 16;
    return (unsigned short)r;
}

static __device__ __forceinline__ float sgnf(float x) {
    return x > 0.0f ? 1.0f : (x < 0.0f ? -1.0f : 0.0f);
}

static __device__ __forceinline__ float ternf(float x) {
    return x > 0.3f ? 1.0f : (x < -0.3f ? -1.0f : 0.0f);
}

static __device__ __forceinline__ float bspline(float u) {
    float t = fabsf(u);
    if (t < 1.0f) return 0.66666666666666663f - t * t + 0.5f * t * t * t;
    if (t < 2.0f) { float w = 2.0f - t; return 0.16666666666666666f * w * w * w; }
    return 0.0f;
}

// ---------------- K0: prep (WT build) + LayerNorm->bf16 XN, one kernel ----------
// blocks 0..255   : WT[j][d] = W1[d][j] (bf16 transpose, 32x32 tiles)
// blocks 256..287 : WT[256+r][d] = sign(dirs[r][d])
// blocks 288..8479: row = bid-288; XN[row] = bf16(LN(x[row])*gamma+beta)
// The LN part is a pure max-TLP stream (8192 blocks) - HBM latency hidden.
__global__ __launch_bounds__(256) void k_prep_ln(const float* __restrict__ W1,
                                                 const float* __restrict__ dirs,
                                                 const float* __restrict__ gamma,
                                                 const float* __restrict__ beta,
                                                 const float* __restrict__ x,
                                                 unsigned short* __restrict__ WT,
                                                 unsigned short* __restrict__ XN) {
    int bid = blockIdx.x;
    int tid = threadIdx.x;
    if (bid < 256) {
        __shared__ float tile[32][33];
        int ktile = bid & 31;            // d tiles of 32
        int ntile = bid >> 5;            // j tiles of 32
        int tx = tid & 31;
        int ty = tid >> 5;               // 0..7
#pragma unroll
        for (int i = 0; i < 4; ++i) {
            int k = ktile * 32 + ty + i * 8;
            int n = ntile * 32 + tx;
            tile[ty + i * 8][tx] = W1[(size_t)k * HH + n];   // coalesced over n
        }
        __syncthreads();
#pragma unroll
        for (int i = 0; i < 4; ++i) {
            int n = ntile * 32 + ty + i * 8;
            int k = ktile * 32 + tx;
            WT[(size_t)n * DD + k] = f2bf(tile[tx][ty + i * 8]);  // coalesced over k
        }
    } else if (bid < 288) {
        int r = bid - 256;               // 0..31
        float4 v = ((const float4*)(dirs + (size_t)r * DD))[tid];
        ushort4 o;
        o.x = f2bf(sgnf(v.x)); o.y = f2bf(sgnf(v.y));
        o.z = f2bf(sgnf(v.z)); o.w = f2bf(sgnf(v.w));
        ((ushort4*)(WT + (size_t)(HH + r) * DD))[tid] = o;
    } else {
        int row = bid - 288;             // 0..8191
        const float4* xr = (const float4*)(x + (size_t)row * DD);
        float4 v = xr[tid];
        float s  = v.x + v.y + v.z + v.w;
        float sq = v.x * v.x + v.y * v.y + v.z * v.z + v.w * v.w;
#pragma unroll
        for (int off = 32; off; off >>= 1) {
            s  += __shfl_xor(s, off);
            sq += __shfl_xor(sq, off);
        }
        __shared__ float red[8];
        int wid = tid >> 6, lane = tid & 63;
        if (lane == 0) { red[wid] = s; red[wid + 4] = sq; }
        __syncthreads();
        s  = red[0] + red[1] + red[2] + red[3];
        sq = red[4] + red[5] + red[6] + red[7];
        float mu   = s * (1.0f / DD);
        float var  = sq * (1.0f / DD) - mu * mu;
        float rstd = rsqrtf(var + 1e-5f);
        float4 gm = ((const float4*)gamma)[tid];
        float4 bt = ((const float4*)beta)[tid];
        ushort4 o;
        o.x = f2bf((v.x - mu) * rstd * gm.x + bt.x);
        o.y = f2bf((v.y - mu) * rstd * gm.y + bt.y);
        o.z = f2bf((v.z - mu) * rstd * gm.z + bt.z);
        o.w = f2bf((v.w - mu) * rstd * gm.w + bt.w);
        ((ushort4*)(XN + (size_t)row * DD))[tid] = o;
    }
}

// ---------------- K1: pure bf16 GEMM  HP = XN @ WT^T ----------------
// BM=32, BN=96, BK=64; grid 768 (XCD-swizzled) = 3 blocks/CU x 4 waves.
// BOTH operands via global_load_lds (deep vmcnt FIFO, zero VGPR cost,
// pre-swizzled sources per rule 21). Simple 2-barrier/kt loop; the 3
// desynced blocks per CU overlap each other's barrier drains.
__global__ __launch_bounds__(256) void k_gemm(const unsigned short* __restrict__ XN,
                                              const unsigned short* __restrict__ WT,
                                              float* __restrict__ HP) {
    __shared__ short Al[2][32 * 64];   // 2 x 4KB
    __shared__ short Bl[2][96 * 64];   // 2 x 12KB
    int tid = threadIdx.x;
    int bid = blockIdx.x;                       // 0..767
    int swz = (bid & 7) * 96 + (bid >> 3);      // bijective XCD swizzle (768=8*96)
    int colblk = swz % 3;
    int rowblk = swz / 3;
    int row0  = rowblk * 32;
    int ncol0 = colblk * 96;
    int lane = tid & 63;
    int wid  = tid >> 6;
    int wm = wid >> 1, wn = wid & 1;
    int l15 = lane & 15, l4 = lane >> 4;

    f32x4 acc[3];
#pragma unroll
    for (int j = 0; j < 3; ++j) acc[j] = (f32x4){0.f, 0.f, 0.f, 0.f};

#define STAGE(kt, buf)                                                           \
    {                                                                            \
        /* A: 32x64 bf16 = 4KB = 1 issue of 256 lanes x 16B */                   \
        {                                                                        \
            int r = tid >> 3, g = tid & 7;                                       \
            const unsigned short* srcA =                                         \
                XN + (size_t)(row0 + r) * DD + (kt) * 64 + ((g * 8) ^ ((r & 7) << 3)); \
            __builtin_amdgcn_global_load_lds(                                    \
                (const __attribute__((address_space(1))) void*)(const void*)srcA,\
                (__attribute__((address_space(3))) void*)(void*)(Al[buf] + tid * 8), \
                16, 0, 0);                                                       \
        }                                                                        \
        /* B: 96x64 bf16 = 12KB = 3 issues */                                    \
        _Pragma("unroll")                                                        \
        for (int ci = 0; ci < 3; ++ci) {                                         \
            int li = ci * 256 + tid;                                             \
            int r  = li >> 3;                                                    \
            int g  = li & 7;                                                     \
            const unsigned short* src =                                          \
                WT + (size_t)(ncol0 + r) * DD + (kt) * 64 + ((g * 8) ^ ((r & 7) << 3)); \
            __builtin_amdgcn_global_load_lds(                                    \
                (const __attribute__((address_space(1))) void*)(const void*)src, \
                (__attribute__((address_space(3))) void*)(void*)(Bl[buf] + li * 8), \
                16, 0, 0);                                                       \
        }                                                                        \
    }

#define COMPUTE(buf)                                                             \
    _Pragma("unroll")                                                            \
    for (int ks = 0; ks < 2; ++ks) {                                             \
        int ra = wm * 16 + l15;                                                  \
        int ca = (ks * 64 + l4 * 16) ^ ((ra & 7) << 4);                          \
        bf16x8 av = *(const bf16x8*)((const char*)Al[buf] + ra * 128 + ca);      \
        bf16x8 bv[3];                                                            \
        _Pragma("unroll")                                                        \
        for (int nf = 0; nf < 3; ++nf) {                                         \
            int rb = wn * 48 + nf * 16 + l15;                                    \
            int cb = (ks * 64 + l4 * 16) ^ ((rb & 7) << 4);                      \
            bv[nf] = *(const bf16x8*)((const char*)Bl[buf] + rb * 128 + cb);     \
        }                                                                        \
        _Pragma("unroll")                                                        \
        for (int nf = 0; nf < 3; ++nf)                                           \
            acc[nf] = __builtin_amdgcn_mfma_f32_16x16x32_bf16(av, bv[nf], acc[nf], 0, 0, 0); \
    }

    STAGE(0, 0);
    __syncthreads();
    for (int kt = 0; kt < 16; ++kt) {
        if (kt < 15) STAGE(kt + 1, (kt + 1) & 1);
        COMPUTE(kt & 1);
        __syncthreads();
    }
#undef STAGE
#undef COMPUTE

    // write: D frag layout col=lane&15, row=(lane>>4)*4+i
#pragma unroll
    for (int nf = 0; nf < 3; ++nf) {
        int colg = ncol0 + wn * 48 + nf * 16 + l15;
        int rl0 = wm * 16 + l4 * 4;
#pragma unroll
        for (int i = 0; i < 4; ++i) {
            HP[(size_t)(row0 + rl0 + i) * NCOLS + colg] = acc[nf][i];
        }
    }
}

// ---------------- K2: per-row epilogue + output ----------------
__global__ __launch_bounds__(256) void k_epilogue(
    const float* __restrict__ HP, const float* __restrict__ x,
    const float* __restrict__ positions, const int* __restrict__ states,
    const float* __restrict__ b1, const float* __restrict__ W2,
    const float* __restrict__ b2, const float* __restrict__ spc,
    const float* __restrict__ sps, const float* __restrict__ dirs,
    const float* __restrict__ ssig, const float* __restrict__ semb,
    const float* __restrict__ smod, const float* __restrict__ oscale,
    float* __restrict__ out) {
    int wid = threadIdx.x >> 6;
    int lane = threadIdx.x & 63;
    int row = blockIdx.x * 4 + wid;

    const float* hrow = HP + (size_t)row * NCOLS;
    float4 hv  = ((const float4*)hrow)[lane];          // h_pre[lane*4 .. +3]
    float4 b1v = ((const float4*)b1)[lane];
    float hs[4] = {hv.x, hv.y, hv.z, hv.w};
    float bs[4] = {b1v.x, b1v.y, b1v.z, b1v.w};
    float sa = 0.f, sb = 0.f;
#pragma unroll
    for (int i = 0; i < 4; ++i) {
        float h = hs[i] + bs[i];
        float g = 0.5f * h * (1.0f + erff(h * 0.70710678118654752f));  // exact gelu
        int j = lane * 4 + i;
        sa += g * W2[2 * j];
        sb += g * W2[2 * j + 1];
    }
#pragma unroll
    for (int off = 32; off; off >>= 1) {
        sa += __shfl_xor(sa, off);
        sb += __shfl_xor(sb, off);
    }
    float av = tanhf(sa + b2[0]);
    float bv = tanhf(sb + b2[1]);

    int st = states[row];
    float comb;
    if (lane < NTT) {
        float content = hrow[HH + lane];
        float pn = positions[row] * ((float)NTT / 2048.0f);
        float u  = (pn - (float)lane) * 0.5f;            // /SPREAD
        float spv = bspline(u);
        const float* sg = ssig + lane * 8;
        const float* se = semb + st * 8;
        float d0 = 0.f;
#pragma unroll
        for (int k = 0; k < 8; ++k) d0 += se[k] * sg[k];
        float temporal = 1.0f / (1.0f + expf(-d0));
        comb = content * spv * temporal;
    } else {
        comb = -__builtin_inff();
    }
    int bi = lane;
#pragma unroll
    for (int off = 32; off; off >>= 1) {
        float ov = __shfl_xor(comb, off);
        int   oi = __shfl_xor(bi, off);
        if (ov > comb || (ov == comb && oi < bi)) { comb = ov; bi = oi; }
    }
    int ia = (int)((av + 1.0f) * 8.0f); ia = ia < 0 ? 0 : (ia > 15 ? 15 : ia);
    int ib = (int)((bv + 1.0f) * 8.0f); ib = ib < 0 ? 0 : (ib > 15 ? 15 : ib);
    const float* cc = spc + (((size_t)bi * 16 + ia) * 16 + ib) * 3;
    float c0 = ternf(cc[0]), c1 = ternf(cc[1]), c2 = ternf(cc[2]);
    float la = (av + 1.0f - (float)ia * 0.125f) * 8.0f;
    float lb = (bv + 1.0f - (float)ib * 0.125f) * 8.0f;
    float scale = (c0 + c1 * la + c2 * lb) * sps[bi];
    float sm = smod[st * NTT + bi];
    float cr = scale * sm * oscale[0];

    const float4* xr = (const float4*)(x + (size_t)row * DD);
    const float4* dr = (const float4*)(dirs + (size_t)bi * DD);
    float4* orow = (float4*)(out + (size_t)row * DD);
#pragma unroll
    for (int i = 0; i < 4; ++i) {
        int idx = i * 64 + lane;
        float4 xv = xr[idx];
        float4 dv = dr[idx];
        float4 o;
        o.x = fmaf(cr, dv.x, xv.x);
        o.y = fmaf(cr, dv.y, xv.y);
        o.z = fmaf(cr, dv.z, xv.z);
        o.w = fmaf(cr, dv.w, xv.w);
        orow[idx] = o;
    }
}

extern "C" void kernel_launch(void* const* d_in, const int* in_sizes, int n_in,
                              void* d_out, int out_size, void* d_ws, size_t ws_size,
                              hipStream_t stream) {
    const float* x     = (const float*)d_in[0];
    const float* pos   = (const float*)d_in[1];
    const int*   st    = (const int*)d_in[2];
    const float* gam   = (const float*)d_in[3];
    const float* bet   = (const float*)d_in[4];
    const float* W1    = (const float*)d_in[5];
    const float* b1    = (const float*)d_in[6];
    const float* W2    = (const float*)d_in[7];
    const float* b2    = (const float*)d_in[8];
    const float* spc   = (const float*)d_in[9];
    const float* sps   = (const float*)d_in[10];
    const float* dirs  = (const float*)d_in[11];
    const float* ssig  = (const float*)d_in[12];
    const float* semb  = (const float*)d_in[13];
    const float* smod  = (const float*)d_in[14];
    const float* oscal = (const float*)d_in[15];
    float* out = (float*)d_out;

    char* ws = (char*)d_ws;
    unsigned short* WT = (unsigned short*)ws;                  // 288*1024 bf16 = 576 KiB
    unsigned short* XN = (unsigned short*)(ws + 1048576);      // 8192*1024 bf16 = 16 MiB
    float* HP          = (float*)(ws + 1048576 + 16777216);    // 8192*288 f32 = 9 MiB

    k_prep_ln<<<288 + NROWS, 256, 0, stream>>>(W1, dirs, gam, bet, x, WT, XN);
    k_gemm<<<768, 256, 0, stream>>>(XN, WT, HP);
    k_epilogue<<<NROWS / 4, 256, 0, stream>>>(HP, x, pos, st, b1, W2, b2, spc, sps,
                                              dirs, ssig, semb, smod, oscal, out);
}

// Round 14
// 44.163 us; speedup vs baseline: 1.1652x; 1.0874x over previous
//
#include <hip/hip_runtime.h>
#include <math.h>

// Problem dims (fixed by setup_inputs)
#define NROWS 8192   // B*T = 4*2048
#define DD    1024
#define HH    256
#define NTT   32
#define NCOLS 288    // HH + NTT
#define HPS   296    // HP LDS row stride (floats)

typedef __attribute__((ext_vector_type(8))) __bf16 bf16x8;
typedef __attribute__((ext_vector_type(4))) float f32x4;

static __device__ __forceinline__ unsigned short f2bf(float f) {
    unsigned int u = __float_as_uint(f);
    unsigned int r = (u + 0x7fffu + ((u >> 16) & 1u)) >> 16;
    return (unsigned short)r;
}

static __device__ __forceinline__ float sgnf(float x) {
    return x > 0.0f ? 1.0f : (x < 0.0f ? -1.0f : 0.0f);
}

static __device__ __forceinline__ float ternf(float x) {
    return x > 0.3f ? 1.0f : (x < -0.3f ? -1.0f : 0.0f);
}

static __device__ __forceinline__ float bspline(float u) {
    float t = fabsf(u);
    if (t < 1.0f) return 0.66666666666666663f - t * t + 0.5f * t * t * t;
    if (t < 2.0f) { float w = 2.0f - t; return 0.16666666666666666f * w * w * w; }
    return 0.0f;
}

// ---------------- K0: prep (WT build) + LayerNorm->bf16 XN (R13 verbatim) -----
// blocks 0..255   : WT[j][d] = W1[d][j] (bf16 transpose, 32x32 tiles)
// blocks 256..287 : WT[256+r][d] = sign(dirs[r][d])
// blocks 288..8479: row = bid-288; XN[row] = bf16(LN(x[row])*gamma+beta)
__global__ __launch_bounds__(256) void k_prep_ln(const float* __restrict__ W1,
                                                 const float* __restrict__ dirs,
                                                 const float* __restrict__ gamma,
                                                 const float* __restrict__ beta,
                                                 const float* __restrict__ x,
                                                 unsigned short* __restrict__ WT,
                                                 unsigned short* __restrict__ XN) {
    int bid = blockIdx.x;
    int tid = threadIdx.x;
    if (bid < 256) {
        __shared__ float tile[32][33];
        int ktile = bid & 31;            // d tiles of 32
        int ntile = bid >> 5;            // j tiles of 32
        int tx = tid & 31;
        int ty = tid >> 5;               // 0..7
#pragma unroll
        for (int i = 0; i < 4; ++i) {
            int k = ktile * 32 + ty + i * 8;
            int n = ntile * 32 + tx;
            tile[ty + i * 8][tx] = W1[(size_t)k * HH + n];   // coalesced over n
        }
        __syncthreads();
#pragma unroll
        for (int i = 0; i < 4; ++i) {
            int n = ntile * 32 + ty + i * 8;
            int k = ktile * 32 + tx;
            WT[(size_t)n * DD + k] = f2bf(tile[tx][ty + i * 8]);  // coalesced over k
        }
    } else if (bid < 288) {
        int r = bid - 256;               // 0..31
        float4 v = ((const float4*)(dirs + (size_t)r * DD))[tid];
        ushort4 o;
        o.x = f2bf(sgnf(v.x)); o.y = f2bf(sgnf(v.y));
        o.z = f2bf(sgnf(v.z)); o.w = f2bf(sgnf(v.w));
        ((ushort4*)(WT + (size_t)(HH + r) * DD))[tid] = o;
    } else {
        int row = bid - 288;             // 0..8191
        const float4* xr = (const float4*)(x + (size_t)row * DD);
        float4 v = xr[tid];
        float s  = v.x + v.y + v.z + v.w;
        float sq = v.x * v.x + v.y * v.y + v.z * v.z + v.w * v.w;
#pragma unroll
        for (int off = 32; off; off >>= 1) {
            s  += __shfl_xor(s, off);
            sq += __shfl_xor(sq, off);
        }
        __shared__ float red[8];
        int wid = tid >> 6, lane = tid & 63;
        if (lane == 0) { red[wid] = s; red[wid + 4] = sq; }
        __syncthreads();
        s  = red[0] + red[1] + red[2] + red[3];
        sq = red[4] + red[5] + red[6] + red[7];
        float mu   = s * (1.0f / DD);
        float var  = sq * (1.0f / DD) - mu * mu;
        float rstd = rsqrtf(var + 1e-5f);
        float4 gm = ((const float4*)gamma)[tid];
        float4 bt = ((const float4*)beta)[tid];
        ushort4 o;
        o.x = f2bf((v.x - mu) * rstd * gm.x + bt.x);
        o.y = f2bf((v.y - mu) * rstd * gm.y + bt.y);
        o.z = f2bf((v.z - mu) * rstd * gm.z + bt.z);
        o.w = f2bf((v.w - mu) * rstd * gm.w + bt.w);
        ((ushort4*)(XN + (size_t)row * DD))[tid] = o;
    }
}

// ---------------- K1: fused GEMM + epilogue ----------------
// Grid 256 (1 block/CU = exactly the work), 576 thr (9 waves, wave-tile 32x32).
// GEMM: HP_local = XN_tile(32x1024) @ WT^T (288x1024), BK=64, both operands
// double-buffered via global_load_lds (pre-swizzled source, rule 21).
// Then HP -> LDS (stride 296) and the per-row epilogue (gelu/W2/tanh/spline/
// argmax), out = x + c*dirs[tile]. No HP HBM round-trip, no stats (LN done).
__global__ __launch_bounds__(576) void k_fused(
    const unsigned short* __restrict__ XN, const unsigned short* __restrict__ WT,
    const float* __restrict__ x,
    const float* __restrict__ positions, const int* __restrict__ states,
    const float* __restrict__ b1, const float* __restrict__ W2,
    const float* __restrict__ b2, const float* __restrict__ spc,
    const float* __restrict__ sps, const float* __restrict__ dirs,
    const float* __restrict__ ssig, const float* __restrict__ semb,
    const float* __restrict__ smod, const float* __restrict__ oscale,
    float* __restrict__ out) {
    __shared__ short Al[2][32 * 64];    // 2 x 4 KB
    __shared__ short Bl[2][NCOLS * 64]; // 2 x 36 KB
    __shared__ float HPl[32 * HPS];     // 37 KB

    int tid  = threadIdx.x;
    int row0 = blockIdx.x * 32;
    int lane = tid & 63;
    int wid  = tid >> 6;                // 0..8 = wave col group (32 cols)
    int l15 = lane & 15, l4 = lane >> 4;

    f32x4 acc[2][2];
#pragma unroll
    for (int i = 0; i < 2; ++i)
#pragma unroll
        for (int j = 0; j < 2; ++j) acc[i][j] = (f32x4){0.f, 0.f, 0.f, 0.f};

#define STAGE(kt, buf)                                                           \
    {                                                                            \
        /* A: 32x64 bf16 = 4KB = 256 granules; threads 0..255 (waves 0-3) */     \
        if (tid < 256) {                                                         \
            int r = tid >> 3, g = tid & 7;                                       \
            const unsigned short* srcA =                                         \
                XN + (size_t)(row0 + r) * DD + (kt) * 64 + ((g * 8) ^ ((r & 7) << 3)); \
            __builtin_amdgcn_global_load_lds(                                    \
                (const __attribute__((address_space(1))) void*)(const void*)srcA,\
                (__attribute__((address_space(3))) void*)(void*)(Al[buf] + tid * 8), \
                16, 0, 0);                                                       \
        }                                                                        \
        /* B: 288x64 bf16 = 36KB = 2304 granules = 4 issues x 576 thr */         \
        _Pragma("unroll")                                                        \
        for (int ci = 0; ci < 4; ++ci) {                                         \
            int li = ci * 576 + tid;                                             \
            int r  = li >> 3;                                                    \
            int g  = li & 7;                                                     \
            const unsigned short* src =                                          \
                WT + (size_t)r * DD + (kt) * 64 + ((g * 8) ^ ((r & 7) << 3));    \
            __builtin_amdgcn_global_load_lds(                                    \
                (const __attribute__((address_space(1))) void*)(const void*)src, \
                (__attribute__((address_space(3))) void*)(void*)(Bl[buf] + li * 8), \
                16, 0, 0);                                                       \
        }                                                                        \
    }

#define COMPUTE(buf)                                                             \
    _Pragma("unroll")                                                            \
    for (int ks = 0; ks < 2; ++ks) {                                             \
        bf16x8 av[2], bv[2];                                                     \
        _Pragma("unroll")                                                        \
        for (int mf = 0; mf < 2; ++mf) {                                         \
            int ra = mf * 16 + l15;                                              \
            int ca = (ks * 64 + l4 * 16) ^ ((ra & 7) << 4);                      \
            av[mf] = *(const bf16x8*)((const char*)Al[buf] + ra * 128 + ca);     \
        }                                                                        \
        _Pragma("unroll")                                                        \
        for (int nf = 0; nf < 2; ++nf) {                                         \
            int rb = wid * 32 + nf * 16 + l15;                                   \
            int cb = (ks * 64 + l4 * 16) ^ ((rb & 7) << 4);                      \
            bv[nf] = *(const bf16x8*)((const char*)Bl[buf] + rb * 128 + cb);     \
        }                                                                        \
        _Pragma("unroll")                                                        \
        for (int mf = 0; mf < 2; ++mf)                                           \
            _Pragma("unroll")                                                    \
            for (int nf = 0; nf < 2; ++nf)                                       \
                acc[mf][nf] = __builtin_amdgcn_mfma_f32_16x16x32_bf16(           \
                    av[mf], bv[nf], acc[mf][nf], 0, 0, 0);                       \
    }

    STAGE(0, 0);
    __syncthreads();
    for (int kt = 0; kt < 16; ++kt) {
        if (kt < 15) STAGE(kt + 1, (kt + 1) & 1);
        COMPUTE(kt & 1);
        __syncthreads();
    }
#undef STAGE
#undef COMPUTE

    // GEMM result -> HPl (D frag: col=lane&15, row=(lane>>4)*4+i)
#pragma unroll
    for (int mf = 0; mf < 2; ++mf) {
#pragma unroll
        for (int nf = 0; nf < 2; ++nf) {
            int colg = wid * 32 + nf * 16 + l15;
            int r0 = mf * 16 + l4 * 4;
#pragma unroll
            for (int i = 0; i < 4; ++i) {
                HPl[(r0 + i) * HPS + colg] = acc[mf][nf][i];
            }
        }
    }
    __syncthreads();

    // ---- per-row epilogue; wave w handles rows w, w+9, w+18, w+27 ----
    float4 b1v = ((const float4*)b1)[lane];
    float w2a[4], w2b[4];
#pragma unroll
    for (int i = 0; i < 4; ++i) {
        int j = lane * 4 + i;
        w2a[i] = W2[2 * j];
        w2b[i] = W2[2 * j + 1];
    }
    float tvs[2] = {0.f, 0.f};
    if (lane < NTT) {
#pragma unroll
        for (int s2 = 0; s2 < 2; ++s2) {
            float d0 = 0.f;
#pragma unroll
            for (int k = 0; k < 8; ++k) d0 += semb[s2 * 8 + k] * ssig[lane * 8 + k];
            tvs[s2] = 1.0f / (1.0f + expf(-d0));
        }
    }
    float osc = oscale[0];
    float bb0 = b2[0], bb1 = b2[1];

    for (int r = wid; r < 32; r += 9) {
        int row = row0 + r;
        float4 hv = *(const float4*)&HPl[r * HPS + lane * 4];
        float hs[4] = {hv.x, hv.y, hv.z, hv.w};
        float bs[4] = {b1v.x, b1v.y, b1v.z, b1v.w};
        float sa = 0.f, sb2 = 0.f;
#pragma unroll
        for (int i = 0; i < 4; ++i) {
            float h = hs[i] + bs[i];
            float g = 0.5f * h * (1.0f + erff(h * 0.70710678118654752f));
            sa  += g * w2a[i];
            sb2 += g * w2b[i];
        }
#pragma unroll
        for (int off = 32; off; off >>= 1) {
            sa  += __shfl_xor(sa, off);
            sb2 += __shfl_xor(sb2, off);
        }
        float av2 = tanhf(sa + bb0);
        float bv2 = tanhf(sb2 + bb1);

        int st = states[row];
        float comb;
        if (lane < NTT) {
            float content = HPl[r * HPS + HH + lane];
            float pn = positions[row] * ((float)NTT / 2048.0f);
            float spv = bspline((pn - (float)lane) * 0.5f);
            comb = content * spv * tvs[st];
        } else {
            comb = -__builtin_inff();
        }
        int bi = lane;
#pragma unroll
        for (int off = 32; off; off >>= 1) {
            float ov = __shfl_xor(comb, off);
            int   oi = __shfl_xor(bi, off);
            if (ov > comb || (ov == comb && oi < bi)) { comb = ov; bi = oi; }
        }
        int ia = (int)((av2 + 1.0f) * 8.0f); ia = ia < 0 ? 0 : (ia > 15 ? 15 : ia);
        int ib = (int)((bv2 + 1.0f) * 8.0f); ib = ib < 0 ? 0 : (ib > 15 ? 15 : ib);
        const float* cc = spc + (((size_t)bi * 16 + ia) * 16 + ib) * 3;
        float c0 = ternf(cc[0]), c1 = ternf(cc[1]), c2 = ternf(cc[2]);
        float la = (av2 + 1.0f - (float)ia * 0.125f) * 8.0f;
        float lb = (bv2 + 1.0f - (float)ib * 0.125f) * 8.0f;
        float scale = (c0 + c1 * la + c2 * lb) * sps[bi];
        float cr = scale * smod[st * NTT + bi] * osc;

        const float4* xr = (const float4*)(x + (size_t)row * DD);
        const float4* dr = (const float4*)(dirs + (size_t)bi * DD);
        float4* orow = (float4*)(out + (size_t)row * DD);
#pragma unroll
        for (int i = 0; i < 4; ++i) {
            int idx = i * 64 + lane;
            float4 xv = xr[idx];
            float4 dv = dr[idx];
            float4 o;
            o.x = fmaf(cr, dv.x, xv.x);
            o.y = fmaf(cr, dv.y, xv.y);
            o.z = fmaf(cr, dv.z, xv.z);
            o.w = fmaf(cr, dv.w, xv.w);
            orow[idx] = o;
        }
    }
}

extern "C" void kernel_launch(void* const* d_in, const int* in_sizes, int n_in,
                              void* d_out, int out_size, void* d_ws, size_t ws_size,
                              hipStream_t stream) {
    const float* x     = (const float*)d_in[0];
    const float* pos   = (const float*)d_in[1];
    const int*   st    = (const int*)d_in[2];
    const float* gam   = (const float*)d_in[3];
    const float* bet   = (const float*)d_in[4];
    const float* W1    = (const float*)d_in[5];
    const float* b1    = (const float*)d_in[6];
    const float* W2    = (const float*)d_in[7];
    const float* b2    = (const float*)d_in[8];
    const float* spc   = (const float*)d_in[9];
    const float* sps   = (const float*)d_in[10];
    const float* dirs  = (const float*)d_in[11];
    const float* ssig  = (const float*)d_in[12];
    const float* semb  = (const float*)d_in[13];
    const float* smod  = (const float*)d_in[14];
    const float* oscal = (const float*)d_in[15];
    float* out = (float*)d_out;

    char* ws = (char*)d_ws;
    unsigned short* WT = (unsigned short*)ws;                  // 288*1024 bf16 = 576 KiB
    unsigned short* XN = (unsigned short*)(ws + 1048576);      // 8192*1024 bf16 = 16 MiB

    k_prep_ln<<<288 + NROWS, 256, 0, stream>>>(W1, dirs, gam, bet, x, WT, XN);
    k_fused<<<NROWS / 32, 576, 0, stream>>>(XN, WT, x, pos, st, b1, W2, b2,
                                            spc, sps, dirs, ssig, semb, smod, oscal, out);
}